// Round 2
// baseline (626.774 us; speedup 1.0000x reference)
//
#include <hip/hip_runtime.h>
#include <stdint.h>

// Viterbi CRF decode: B=1024, T=1024, N=34 (32 tags + START=32 + END=33)
// One wave (64 lanes) per batch: lane j = target state (j<34 active).
// Scores broadcast through per-wave LDS; same-wave DS ops are in-order ->
// NO barriers anywhere in the forward recursion. 1024 waves = 1/SIMD,
// kernel is pure VALU-issue-bound.
#define BB 1024
#define TT 1024
#define NN 34
#define NEGV -6969.0f

typedef float v2f __attribute__((ext_vector_type(2)));
typedef float v4f __attribute__((ext_vector_type(4)));

__device__ __forceinline__ float fmax3(float a, float b, float c) {
    return fmaxf(fmaxf(a, b), c);   // fuses to v_max3_f32
}

__global__ __launch_bounds__(256, 1) void viterbi_wave(
        const float* __restrict__ feat,   // [B,T,34]
        const float* __restrict__ trans,  // [34,34]
        unsigned char* __restrict__ bpg,  // workspace [B,T,34] backpointers
        float* __restrict__ out)          // best[B] ++ path[B,T+1]
{
    __shared__ __align__(16) float sc[4][64];      // per-wave score broadcast
    __shared__ unsigned char Fm[4][16][NN];        // backtrack level-1 results
    __shared__ int Eb[4][16];                      // backtrack level-2 carries

    const int wid  = threadIdx.x >> 6;   // wave in block = batch slot
    const int lane = threadIdx.x & 63;
    const int j    = lane;               // target state
    const int jm   = (j < NN) ? j : (NN - 1);   // clamp for idle lanes
    const bool act = (j < NN);
    const int bg   = blockIdx.x * 4 + wid;

    // ---- per-lane constants: transitions row j (34 floats, packed)
    v4f t4[8]; v2f t2;
    {
        const float* trow = trans + jm * NN;
#pragma unroll
        for (int i = 0; i < 8; ++i)
            t4[i] = (v4f){trow[4*i], trow[4*i+1], trow[4*i+2], trow[4*i+3]};
        t2 = (v2f){trow[32], trow[33]};
    }
    // END-transition row (uniform across lanes -> scalarizes)
    v4f e4[8]; v2f e2;
    {
        const float* erow = trans + (NN - 1) * NN;
#pragma unroll
        for (int i = 0; i < 8; ++i)
            e4[i] = (v4f){erow[4*i], erow[4*i+1], erow[4*i+2], erow[4*i+3]};
        e2 = (v2f){erow[32], erow[33]};
    }

    const float* fp = feat + (size_t)bg * TT * NN + jm;
    unsigned char* bpt = bpg + (size_t)bg * TT * NN + j;

    float* const scW = &sc[wid][0];
    const v4f* const S4 = (const v4f*)scW;
    const v2f* const S2 = (const v2f*)scW;

    // ---- init scores (lane k holds score[k]); lanes>=34 junk, never read
    scW[lane] = (lane == 32) ? 0.0f : NEGV;

    // first broadcast read (same-wave in-order DS after the write above)
    v4f q[8]; v2f q8;
#pragma unroll
    for (int i = 0; i < 8; ++i) q[i] = S4[i];
    q8 = S2[16];

    // 4-deep feature prefetch ring (t = 0..3)
    float fr0 = fp[0*NN], fr1 = fp[1*NN], fr2 = fp[2*NN], fr3 = fp[3*NN];

    // one Viterbi step. exact fp order (s+f)+tr; argmax = first index at max.
    // order inside: adds/tree -> write m -> refill reads (latency hidden by
    // the argmax eq-scan that follows) -> bp store.
    auto vstep = [&](float fv, unsigned char* bpw) {
        const v4f f4 = (v4f){fv, fv, fv, fv};
        const v2f f2 = (v2f){fv, fv};
        v4f w[8]; v2f w8;
#pragma unroll
        for (int i = 0; i < 8; ++i) w[i] = (q[i] + f4) + t4[i];  // v_pk_add_f32
        w8 = (q8 + f2) + t2;
        float wv[NN];
#pragma unroll
        for (int i = 0; i < 8; ++i) {
            wv[4*i+0] = w[i].x; wv[4*i+1] = w[i].y;
            wv[4*i+2] = w[i].z; wv[4*i+3] = w[i].w;
        }
        wv[32] = w8.x; wv[33] = w8.y;
        float a[12];
#pragma unroll
        for (int i = 0; i < 11; ++i) a[i] = fmax3(wv[3*i], wv[3*i+1], wv[3*i+2]);
        a[11] = wv[33];
        float b0 = fmax3(a[0], a[1], a[2]), b1 = fmax3(a[3], a[4], a[5]);
        float b2 = fmax3(a[6], a[7], a[8]), b3 = fmax3(a[9], a[10], a[11]);
        float m = fmaxf(fmaxf(b0, b1), fmaxf(b2, b3));
        scW[lane] = m;                       // publish score[j] for next step
#pragma unroll
        for (int i = 0; i < 8; ++i) q[i] = S4[i];   // refill (in-order RAW)
        q8 = S2[16];
        int am = 127;
#pragma unroll
        for (int k = NN - 1; k >= 0; --k) am = (wv[k] == m) ? k : am;
        if (act) *bpw = (unsigned char)am;
    };

    // ---- forward: 255 iters x 4 steps (prefetch t+4) + 4-step epilogue
    for (int n = 0; n < 255; ++n) {
        { float f = fr0; fr0 = fp[4*NN]; vstep(f, bpt + 0*NN); }
        { float f = fr1; fr1 = fp[5*NN]; vstep(f, bpt + 1*NN); }
        { float f = fr2; fr2 = fp[6*NN]; vstep(f, bpt + 2*NN); }
        { float f = fr3; fr3 = fp[7*NN]; vstep(f, bpt + 3*NN); }
        fp += 4*NN; bpt += 4*NN;
    }
    vstep(fr0, bpt + 0*NN);
    vstep(fr1, bpt + 1*NN);
    vstep(fr2, bpt + 2*NN);
    vstep(fr3, bpt + 3*NN);
    // q now holds the broadcast of final scores (t=1024) in every lane.

    // ---- end transition + final argmax (redundantly in all lanes, no LDS)
    int bi;
    float bm;
    {
        v4f w[8]; v2f w8;
#pragma unroll
        for (int i = 0; i < 8; ++i) w[i] = q[i] + e4[i];
        w8 = q8 + e2;
        float wv[NN];
#pragma unroll
        for (int i = 0; i < 8; ++i) {
            wv[4*i+0] = w[i].x; wv[4*i+1] = w[i].y;
            wv[4*i+2] = w[i].z; wv[4*i+3] = w[i].w;
        }
        wv[32] = w8.x; wv[33] = w8.y;
        float a[12];
#pragma unroll
        for (int i = 0; i < 11; ++i) a[i] = fmax3(wv[3*i], wv[3*i+1], wv[3*i+2]);
        a[11] = wv[33];
        float b0 = fmax3(a[0], a[1], a[2]), b1 = fmax3(a[3], a[4], a[5]);
        float b2 = fmax3(a[6], a[7], a[8]), b3 = fmax3(a[9], a[10], a[11]);
        bm = fmaxf(fmaxf(b0, b1), fmaxf(b2, b3));
        bi = 127;
#pragma unroll
        for (int k = NN - 1; k >= 0; --k) bi = (wv[k] == bm) ? k : bi;
    }
    if (lane == 0) out[bg] = bm;

    // ---- backtrack on this wave's own bp (stores by this wave; L2-resident)
    asm volatile("s_waitcnt vmcnt(0)" ::: "memory");
    const unsigned char* __restrict__ bb = bpg + (size_t)bg * TT * NN;

    // level-1: 16 chunks x 64 steps x 34 hypotheses; lane (c=lane>>2, sub),
    // 9 interleaved chases per lane (ILP hides L2 latency)
    {
        const int c = lane >> 2;
        const int sub = lane & 3;
        int mv[9];
#pragma unroll
        for (int qi = 0; qi < 9; ++qi) {
            int x = sub + 4 * qi;
            mv[qi] = (x < NN) ? x : (NN - 1);
        }
        const unsigned char* cb = bb + (size_t)c * 64 * NN;
        for (int i = 63; i >= 0; --i) {
            const unsigned char* rb = cb + (size_t)i * NN;
#pragma unroll
            for (int qi = 0; qi < 9; ++qi) mv[qi] = rb[mv[qi]];
        }
#pragma unroll
        for (int qi = 0; qi < 9; ++qi) {
            int x = sub + 4 * qi;
            if (x < NN) Fm[wid][c][x] = (unsigned char)mv[qi];
        }
    }

    // level-2: serial 16-chunk scan (same-wave in-order DS, no barrier)
    if (lane == 0) {
        int e = bi;
        Eb[wid][15] = e;
        for (int c = 15; c >= 1; --c) { e = Fm[wid][c][e]; Eb[wid][c - 1] = e; }
    }

    // emit: winning hypothesis per chunk re-chases and writes the path
    float* po = out + BB + (size_t)bg * (TT + 1);
    if (lane < 16) {
        int c = lane;
        int m = Eb[wid][c];
        for (int i = 63; i >= 0; --i) {
            m = bb[(size_t)((c * 64 + i) * NN) + m];
            po[c * 64 + i] = (float)m;
        }
    }
    if (lane == 16) po[TT] = (float)bi;
}

extern "C" void kernel_launch(void* const* d_in, const int* in_sizes, int n_in,
                              void* d_out, int out_size, void* d_ws, size_t ws_size,
                              hipStream_t stream) {
    const float* feat  = (const float*)d_in[0];   // [1024,1024,34]
    const float* trans = (const float*)d_in[1];   // [34,34]
    float* out = (float*)d_out;                   // 1024 + 1024*1025 floats
    unsigned char* bp = (unsigned char*)d_ws;     // 35,651,584 B backpointers

    viterbi_wave<<<BB / 4, 256, 0, stream>>>(feat, trans, bp, out);
}